// Round 10
// baseline (241.438 us; speedup 1.0000x reference)
//
#include <hip/hip_runtime.h>
#include <math.h>

typedef unsigned u32;
typedef _Float16 f16x8 __attribute__((ext_vector_type(8)));
typedef float    f32x16 __attribute__((ext_vector_type(16)));

static __device__ __forceinline__ u32 pack2(_Float16 a, _Float16 b) {
    union { _Float16 h[2]; u32 u; } v;
    v.h[0] = a; v.h[1] = b;
    return v.u;
}

// ws (halves): h1 13,271,040 | A1 129,024 (19,456 used) | A2 576,000 (158,080 used) | part 8,294,400

// ---------------- A-pack: conv1 bank-padded gather table ----------------
// A1'[kh8][kw7][kd7][oc5][j8] strides (u32): oc 4, kd 20, kw 164, kh 1164
//   -> gather addr ≡ 4m (mod 32), conflict-free. kh=7 row + pads = zeros.
__global__ __launch_bounds__(256) void pack_A1p(
    const float* __restrict__ w1, _Float16* __restrict__ A1)
{
    int i = blockIdx.x * 256 + threadIdx.x;      // u32 index, 9728 total (38 blocks)
    if (i >= 9728) return;
    u32 outv = 0u;
    int kh = i / 1164, r = i % 1164;
    if (kh < 7 && r < 1148) {
        int kw = r / 164, r2 = r % 164;
        if (r2 < 140) {
            int kd = r2 / 20, r3 = r2 % 20;
            int oc = r3 / 4, j2 = r3 % 4;
            int j0 = 2 * j2, j1 = 2 * j2 + 1;
            const float* wb = w1 + oc * 2401 + kh * 343 + kw * 49 + kd * 7;
            _Float16 v0 = (j0 < 7) ? (_Float16)wb[j0] : (_Float16)0.f;
            _Float16 v1 = (j1 < 7) ? (_Float16)wb[j1] : (_Float16)0.f;
            outv = pack2(v0, v1);
        }
    }
    ((u32*)A1)[i] = outv;
}

// ---------------- A-pack: conv2 bank-padded gather table ----------------
// A2'[ci5][kh8][kw7][kd7][oc10][j8] strides (u32): oc 4, kd 40, kw 280, kh 1976
//   -> gather addr ≡ 8dh+4oc (mod 32): max 4 lanes/16B-group = conflict-free.
//   kh=7 row + kw pad = zeros. Per ci 15808 u32; total 79040 u32.
__global__ __launch_bounds__(256) void pack_A2p(
    const float* __restrict__ w2, _Float16* __restrict__ A2)
{
    int i = blockIdx.x * 256 + threadIdx.x;      // u32 index, 79040 total (309 blocks)
    if (i >= 79040) return;
    int ci = i / 15808, r = i % 15808;
    int kh = r / 1976, r2 = r % 1976;
    u32 outv = 0u;
    if (kh < 7 && r2 < 1960) {
        int kw = r2 / 280, r3 = r2 % 280;
        int kd = r3 / 40, r4 = r3 % 40;
        int oc = r4 / 4, j2 = r4 % 4;
        int j0 = 2 * j2, j1 = 2 * j2 + 1;
        const float* wb = w2 + oc * 12005 + ci * 2401 + kh * 343 + kw * 49 + kd * 7;
        _Float16 v0 = (j0 < 7) ? (_Float16)wb[j0] : (_Float16)0.f;
        _Float16 v1 = (j1 < 7) ? (_Float16)wb[j1] : (_Float16)0.f;
        outv = pack2(v0, v1);
    }
    ((u32*)A2)[i] = outv;
}

// ---------------- conv1: 32x32x16 MFMA, windowed LDS, 4 waves ----------------
// block=(b,OH,OWp): M=30=(dw2,dh3,oc5), N=288=(u2,od12,ot12) -> 9 nt,
// K = 9 se x 28 k2(2 taps x kt8).
// Slab row stride 48 (≡16 mod 32): read class = n mod 8 -> ALL B-reads bank-perfect
// (every 32-lane run hits each 4-bank class exactly 4x; taps/g add uniform shifts).
// Staged writes concentrate in 2 classes (16*tid mod 32) — accepted cost.
// A via persistent bank-padded LDS gather table (see pack_A1p):
//   lane addr = AOFF + kh*1164 + 4oc - 164dw + (164we + 20kd)   [we,kd compile-time per (k2,g)]
//   invalid kh/kw -> zero slot at kh=7 (+164 bias). junk lanes (col>=30): clamp+offset.
#define C1_SLAB 8640
#define C1_AOFF 8640
#define C1_LDS  (8640 + 9728)                    // 73.5 KB -> 2 blocks/CU
__global__ __launch_bounds__(256, 2) void conv1_mfma(
    const float* __restrict__ x, const _Float16* __restrict__ A1,
    const float* __restrict__ b1, _Float16* __restrict__ h1)
{
    __shared__ u32 lds[C1_LDS];
    int tid = threadIdx.x;
    int lane = tid & 63;
    int wave = tid >> 6;
    int col = lane & 31;
    int g = lane >> 5;

    int bid = (int)blockIdx.x;                   // 1536 = 8*192
    int lbid = (bid & 7) * 192 + (bid >> 3);     // XCD chunk swizzle
    int OWp = lbid % 3;
    int OH = (lbid / 3) & 3;
    int b = lbid / 12;

    int qn[3], u_[3], od_[3], ot_[3];
    #pragma unroll
    for (int s = 0; s < 3; ++s) {
        int nt = wave + 4 * s;
        int n = (nt <= 8) ? nt * 32 + col : col;
        int u = n / 144, r2 = n % 144;
        int od = r2 / 12, ot = r2 % 12;
        u_[s] = u; od_[s] = od; ot_[s] = ot;
        qn[s] = (u * 36 + od) * 48 + ot * 4;
    }

    f32x16 acc0, acc1, acc2;
    #pragma unroll
    for (int q = 0; q < 16; ++q) { acc0[q] = 0.f; acc1[q] = 0.f; acc2[q] = 0.f; }

    const float* xbase = x + (size_t)b * 104976;
    int w10 = tid / 18, id18 = tid % 18;
    int iw = 4 * OWp + w10;
    bool stager = (tid < 180);

    // lane A-gather constants (bank-perfect layout)
    int mc = (col < 30) ? col : 29;
    int am_dw = mc / 15, am_dh = (mc % 15) / 5, am_oc = mc % 5;
    int jadd = 4 * (col - mc);                   // 0; 4/8 for col 30/31
    int vlane = 4 * am_oc - 164 * am_dw + jadd;
    int zbase = C1_AOFF + 8312 + vlane;          // zero slot (kh=7 +164 bias)
    bool eLo = (am_dw == 1);                     // we==0 edge (k2<=2)
    bool e3  = (am_dw == 1) && (g == 0);         // k2==3, tap0 we==0
    bool e24 = (am_dw == 0) && (g == 1);         // k2==24, tap1 we==7
    bool eHi = (am_dw == 0);                     // we==7 edge (k2>=25)

    float2 xr[9];
    {   // prologue: A' table into LDS; preload x(se=0)
        const uint4* asrc = (const uint4*)A1;
        uint4* adst = (uint4*)(lds + C1_AOFF);
        #pragma unroll
        for (int i = 0; i < 10; ++i) {
            int q = tid + 256 * i;
            if (q < 2432) adst[q] = asrc[q];
        }
        if (stager) {
            const float2* src = (const float2*)(xbase + (3 * OH) * 5832 + iw * 324 + id18 * 18);
            #pragma unroll
            for (int q = 0; q < 9; ++q) xr[q] = src[q];
        }
    }

    for (int se = 0; se < 9; ++se) {
        int kh = se - am_dh;
        int vbase = (kh >= 0 && kh < 7) ? (C1_AOFF + kh * 1164 + vlane) : zbase;

        __syncthreads();                         // prior compute done (covers prologue at se=0)
        if (stager) {
            _Float16 h[19];
            #pragma unroll
            for (int q = 0; q < 9; ++q) { h[2*q] = (_Float16)xr[q].x; h[2*q+1] = (_Float16)xr[q].y; }
            h[18] = (_Float16)0.f;
            u32 e[9], o[9];
            #pragma unroll
            for (int q = 0; q < 9; ++q) e[q] = pack2(h[2*q], h[2*q+1]);
            #pragma unroll
            for (int q = 0; q < 9; ++q) o[q] = pack2(h[2*q+1], (q < 8) ? h[2*q+2] : h[18]);
            int base = tid * 48;
            #pragma unroll
            for (int ot = 0; ot < 12; ++ot) {
                uint4 w;
                if ((ot & 1) == 0) { const int q = ot >> 1;   w = (uint4){e[q], e[q+1], e[q+2], e[q+3]}; }
                else               { const int q = (ot-1)>>1; w = (uint4){o[q], o[q+1], o[q+2], o[q+3]}; }
                *(uint4*)(&lds[base + ot * 4]) = w;
            }
        }
        __syncthreads();

        if (se < 8 && stager) {                  // prefetch next stage into regs
            const float2* src = (const float2*)(xbase + (3 * OH + se + 1) * 5832 + iw * 324 + id18 * 18);
            #pragma unroll
            for (int q = 0; q < 9; ++q) xr[q] = src[q];
        }

        #pragma unroll
        for (int k2 = 0; k2 < 28; ++k2) {
            const int t0 = 2 * k2, t1 = 2 * k2 + 1;
            const int c0 = ((t0 / 7) * 18 + (t0 % 7)) * 48;
            const int c1 = ((t1 / 7) * 18 + (t1 % 7)) * 48;
            const int ca0 = 164 * (t0 / 7) + 20 * (t0 % 7);
            const int ca1 = 164 * (t1 / 7) + 20 * (t1 % 7);
            int qoff = g ? c1 : c0;
            int ca   = g ? ca1 : ca0;
            int abase;
            if (k2 <= 2)       abase = eLo ? zbase : vbase;
            else if (k2 == 3)  abase = e3  ? zbase : vbase;
            else if (k2 == 24) abase = e24 ? zbase : vbase;
            else if (k2 >= 25) abase = eHi ? zbase : vbase;
            else               abase = vbase;
            f16x8 af = *(const f16x8*)(lds + abase + ca);
            f16x8 bf0 = *(const f16x8*)(lds + qn[0] + qoff);
            f16x8 bf1 = *(const f16x8*)(lds + qn[1] + qoff);
            acc0 = __builtin_amdgcn_mfma_f32_32x32x16_f16(af, bf0, acc0, 0, 0, 0);
            acc1 = __builtin_amdgcn_mfma_f32_32x32x16_f16(af, bf1, acc1, 0, 0, 0);
            if (wave == 0) {
                f16x8 bf2 = *(const f16x8*)(lds + qn[2] + qoff);
                acc2 = __builtin_amdgcn_mfma_f32_32x32x16_f16(af, bf2, acc2, 0, 0, 0);
            }
        }
    }

    // store: C row = (r&3)+8*(r>>2)+4*g -> m = dw*15+dh*5+oc; col -> (u,od,ot)
    #pragma unroll
    for (int s = 0; s < 3; ++s) {
        if (s == 2 && wave != 0) continue;
        f32x16 a = (s == 0) ? acc0 : ((s == 1) ? acc1 : acc2);
        int ow_b = 4 * OWp + 2 * u_[s];
        #pragma unroll
        for (int r = 0; r < 16; ++r) {
            const int m0 = (r & 3) + 8 * (r >> 2);
            const int m1 = m0 + 4;
            const int dw0 = m0 / 15, dh0 = (m0 % 15) / 5, oc0 = m0 % 5;
            const int dw1 = m1 / 15, dh1 = (m1 % 15) / 5, oc1 = m1 % 5;
            if (m1 >= 30 && g) continue;
            int dw = g ? dw1 : dw0;
            int dh = g ? dh1 : dh0;
            int oc = g ? oc1 : oc0;
            float bv = g ? b1[oc1] : b1[oc0];
            float v = fmaxf(a[r] + bv, 0.f);
            h1[(size_t)b * 103680 + oc * 20736 + (3 * OH + dh) * 1728
               + (ow_b + dw) * 144 + od_[s] * 12 + ot_[s]] = (_Float16)v;
        }
    }
}

// ---------------- conv2: 32x32x16 MFMA, gather-A table, ci-split ----------------
// block=(b,OH2,ci): M=30=(dh3,oc10), N=216 -> 7 nt, K = 9 she x 25 k2.
// A via persistent bank-padded gather table (per ci, see pack_A2p):
//   lane addr = AOFF + kh*1976 + 4oc + (280kw + 40kd)  [kw,kd compile-time per (k2,g)]
//   invalid kh or tap49 -> zero slot (kh=7 row). No per-she A restaging.
#define C2_SLAB 4032
#define C2_AOFF 4032
#define C2_LDS  (4032 + 15808)                   // 77.5 KB -> 2 blocks/CU
__global__ __launch_bounds__(256, 2) void conv2_mfma(
    const _Float16* __restrict__ h1, const _Float16* __restrict__ A2,
    _Float16* __restrict__ part)
{
    __shared__ u32 lds[C2_LDS];
    int tid = threadIdx.x;
    int lane = tid & 63;
    int wave = tid >> 6;
    int col = lane & 31;
    int g = lane >> 5;

    int bid = (int)blockIdx.x;                   // 1280 = 8*160
    int lbid = (bid & 7) * 160 + (bid >> 3);
    int ci = lbid % 5;
    int OH2 = (lbid / 5) & 1;
    int b = lbid / 10;

    int qn[2], n_[2];
    #pragma unroll
    for (int s = 0; s < 2; ++s) {
        int nt = wave + 4 * s;
        int n = nt * 32 + col;                   // nt<=6 -> n<224
        n_[s] = n;
        int nc = (n < 216) ? n : 215;
        int ow = nc / 36, rem = nc % 36;
        int od = rem / 6, ot = rem % 6;
        qn[s] = (ow * 12 + od) * 28 + ot * 4;
    }

    f32x16 acc0, acc1;
    #pragma unroll
    for (int q = 0; q < 16; ++q) { acc0[q] = 0.f; acc1[q] = 0.f; }

    const _Float16* hbase = h1 + (size_t)b * 103680 + ci * 20736;
    int iw = tid / 12, id12 = tid % 12;
    bool stager = (tid < 144);

    // lane A-gather constants
    int mc = (col < 30) ? col : 29;
    int am_dh = mc / 10, am_oc = mc % 10;
    int jadd = 4 * (col - mc);                   // 0; 4/8 for col 30/31
    int vlane = 4 * am_oc + jadd;
    int zb = C2_AOFF + 13832 + vlane;            // kh=7 zero row

    uint2 xr[3];
    {   // prologue: table into LDS (3952 uint4); preload h1(she=0)
        const uint4* asrc = (const uint4*)A2 + (size_t)ci * 3952;
        uint4* adst = (uint4*)(lds + C2_AOFF);
        #pragma unroll
        for (int i = 0; i < 16; ++i) {
            int q = tid + 256 * i;
            if (q < 3952) adst[q] = asrc[q];
        }
        if (stager) {
            const uint2* src = (const uint2*)(hbase + (3 * OH2) * 1728 + iw * 144 + id12 * 12);
            #pragma unroll
            for (int q = 0; q < 3; ++q) xr[q] = src[q];
        }
    }

    for (int she = 0; she < 9; ++she) {
        int kh = she - am_dh;
        int vb = (kh >= 0 && kh < 7) ? (C2_AOFF + kh * 1976 + vlane) : zb;

        __syncthreads();                         // prior compute done (covers prologue at she=0)
        if (stager) {
            _Float16 h[14];
            *(uint2*)&h[0] = xr[0]; *(uint2*)&h[4] = xr[1]; *(uint2*)&h[8] = xr[2];
            h[12] = (_Float16)0.f;
            u32 e[6], o[6];
            #pragma unroll
            for (int q = 0; q < 6; ++q) e[q] = pack2(h[2*q], h[2*q+1]);
            #pragma unroll
            for (int q = 0; q < 6; ++q) o[q] = pack2(h[2*q+1], (q < 5) ? h[2*q+2] : h[12]);
            int base = tid * 28;
            #pragma unroll
            for (int ot = 0; ot < 6; ++ot) {
                uint4 w;
                if ((ot & 1) == 0) { const int q = ot >> 1;   w = (uint4){e[q], e[q+1], e[q+2], e[q+3]}; }
                else               { const int q = (ot-1)>>1; w = (uint4){o[q], o[q+1], o[q+2], o[q+3]}; }
                *(uint4*)(&lds[base + ot * 4]) = w;
            }
        }
        __syncthreads();

        if (she < 8 && stager) {                 // prefetch next stage into regs
            const uint2* src = (const uint2*)(hbase + (3 * OH2 + she + 1) * 1728 + iw * 144 + id12 * 12);
            #pragma unroll
            for (int q = 0; q < 3; ++q) xr[q] = src[q];
        }

        #pragma unroll
        for (int k2 = 0; k2 < 25; ++k2) {
            const int t0 = 2 * k2, t1 = 2 * k2 + 1;
            const int c0 = ((t0 / 7) * 12 + (t0 % 7)) * 28;
            const int c1 = (t1 < 49) ? ((t1 / 7) * 12 + (t1 % 7)) * 28 : 0;
            const int a0 = 280 * (t0 / 7) + 40 * (t0 % 7);
            const int a1 = (t1 < 49) ? (280 * (t1 / 7) + 40 * (t1 % 7)) : 0;
            int qoff = g ? c1 : c0;
            int ca   = g ? a1 : a0;
            int ab = (k2 == 24 && g) ? zb : vb;  // tap 49 invalid
            f16x8 af = *(const f16x8*)(lds + ab + ca);
            f16x8 bf0 = *(const f16x8*)(lds + qn[0] + qoff);
            acc0 = __builtin_amdgcn_mfma_f32_32x32x16_f16(af, bf0, acc0, 0, 0, 0);
            if (wave < 3) {
                f16x8 bf1 = *(const f16x8*)(lds + qn[1] + qoff);
                acc1 = __builtin_amdgcn_mfma_f32_32x32x16_f16(af, bf1, acc1, 0, 0, 0);
            }
        }
    }

    // store partials: part[ci][b*6+oh][oc][216]; m = dh*10+oc
    #pragma unroll
    for (int s = 0; s < 2; ++s) {
        if (s == 1 && wave >= 3) continue;
        if (n_[s] >= 216) continue;
        f32x16 a = (s == 0) ? acc0 : acc1;
        #pragma unroll
        for (int r = 0; r < 16; ++r) {
            const int m0 = (r & 3) + 8 * (r >> 2);
            const int m1 = m0 + 4;
            const int dh0 = m0 / 10, oc0 = m0 % 10;
            const int dh1 = m1 / 10, oc1 = m1 % 10;
            if (m1 >= 30 && g) continue;
            int dh = g ? dh1 : dh0;
            int oc = g ? oc1 : oc0;
            int oh = 3 * OH2 + dh;
            part[((size_t)(ci * 768 + b * 6 + oh) * 10 + oc) * 216 + n_[s]] = (_Float16)a[r];
        }
    }
}

// ---------------- fused: 5-ci reduce + bias + ReLU + linear + sigmoid ----------------
__global__ __launch_bounds__(256) void out_fused(
    const _Float16* __restrict__ part, const float* __restrict__ b2,
    const float* __restrict__ wl, const float* __restrict__ bl,
    float* __restrict__ out)
{
    int b = blockIdx.x;
    int tid = threadIdx.x;
    float s = 0.f;
    for (int i = tid; i < 12960; i += 256) {
        int oc = i / 1296;
        int rem = i % 1296;
        int oh = rem / 216;
        int n = rem % 216;
        float v = 0.f;
        #pragma unroll
        for (int ci = 0; ci < 5; ++ci)
            v += (float)part[((size_t)(ci * 768 + b * 6 + oh) * 10 + oc) * 216 + n];
        v = fmaxf(v + b2[oc], 0.f);
        s += v * wl[i];
    }
    #pragma unroll
    for (int off = 32; off > 0; off >>= 1)
        s += __shfl_down(s, off, 64);
    __shared__ float wsum[4];
    int wave = tid >> 6;
    if ((tid & 63) == 0) wsum[wave] = s;
    __syncthreads();
    if (tid == 0) {
        float tot = wsum[0] + wsum[1] + wsum[2] + wsum[3] + bl[0];
        out[b] = 1.f / (1.f + expf(-tot));
    }
}

extern "C" void kernel_launch(void* const* d_in, const int* in_sizes, int n_in,
                              void* d_out, int out_size, void* d_ws, size_t ws_size,
                              hipStream_t stream) {
    const float* x  = (const float*)d_in[0];
    const float* w1 = (const float*)d_in[1];
    const float* b1 = (const float*)d_in[2];
    const float* w2 = (const float*)d_in[3];
    const float* b2 = (const float*)d_in[4];
    const float* wl = (const float*)d_in[5];
    const float* bl = (const float*)d_in[6];
    float* out = (float*)d_out;

    _Float16* h1   = (_Float16*)d_ws;            // 13,271,040
    _Float16* A1   = h1 + 13271040;              //    129,024 (19,456 used)
    _Float16* A2   = A1 + 129024;                //    576,000 (158,080 used)
    _Float16* part = A2 + 576000;                //  8,294,400

    pack_A1p<<<38, 256, 0, stream>>>(w1, A1);
    pack_A2p<<<309, 256, 0, stream>>>(w2, A2);
    conv1_mfma<<<1536, 256, 0, stream>>>(x, A1, b1, h1);
    conv2_mfma<<<1280, 256, 0, stream>>>(h1, A2, part);
    out_fused<<<128, 256, 0, stream>>>(part, b2, wl, bl, out);
}

// Round 11
// 232.841 us; speedup vs baseline: 1.0369x; 1.0369x over previous
//
#include <hip/hip_runtime.h>
#include <math.h>

typedef unsigned u32;
typedef _Float16 f16x8 __attribute__((ext_vector_type(8)));
typedef float    f32x16 __attribute__((ext_vector_type(16)));

static __device__ __forceinline__ u32 pack2(_Float16 a, _Float16 b) {
    union { _Float16 h[2]; u32 u; } v;
    v.h[0] = a; v.h[1] = b;
    return v.u;
}

// ws (halves): h1 13,271,040 | A1 129,024 (19,456 used) | A2 576,000 (158,080 used) | part 8,294,400

// ---------------- A-pack: conv1 bank-padded gather table ----------------
// A1'[kh8][kw7][kd7][oc5][j8] strides (u32): oc 4, kd 20, kw 164, kh 1164
//   -> gather addr ≡ 4m (mod 32), conflict-free. kh=7 row + pads = zeros.
__global__ __launch_bounds__(256) void pack_A1p(
    const float* __restrict__ w1, _Float16* __restrict__ A1)
{
    int i = blockIdx.x * 256 + threadIdx.x;      // u32 index, 9728 total (38 blocks)
    if (i >= 9728) return;
    u32 outv = 0u;
    int kh = i / 1164, r = i % 1164;
    if (kh < 7 && r < 1148) {
        int kw = r / 164, r2 = r % 164;
        if (r2 < 140) {
            int kd = r2 / 20, r3 = r2 % 20;
            int oc = r3 / 4, j2 = r3 % 4;
            int j0 = 2 * j2, j1 = 2 * j2 + 1;
            const float* wb = w1 + oc * 2401 + kh * 343 + kw * 49 + kd * 7;
            _Float16 v0 = (j0 < 7) ? (_Float16)wb[j0] : (_Float16)0.f;
            _Float16 v1 = (j1 < 7) ? (_Float16)wb[j1] : (_Float16)0.f;
            outv = pack2(v0, v1);
        }
    }
    ((u32*)A1)[i] = outv;
}

// ---------------- A-pack: conv2 bank-padded gather table ----------------
// A2'[ci5][kh8][kw7][kd7][oc10][j8] strides (u32): oc 4, kd 40, kw 280, kh 1976
//   -> gather addr ≡ 8dh+4oc (mod 32): max 4 lanes/16B-group = conflict-free.
//   kh=7 row + kw pad = zeros. Per ci 15808 u32; total 79040 u32.
__global__ __launch_bounds__(256) void pack_A2p(
    const float* __restrict__ w2, _Float16* __restrict__ A2)
{
    int i = blockIdx.x * 256 + threadIdx.x;      // u32 index, 79040 total (309 blocks)
    if (i >= 79040) return;
    int ci = i / 15808, r = i % 15808;
    int kh = r / 1976, r2 = r % 1976;
    u32 outv = 0u;
    if (kh < 7 && r2 < 1960) {
        int kw = r2 / 280, r3 = r2 % 280;
        int kd = r3 / 40, r4 = r3 % 40;
        int oc = r4 / 4, j2 = r4 % 4;
        int j0 = 2 * j2, j1 = 2 * j2 + 1;
        const float* wb = w2 + oc * 12005 + ci * 2401 + kh * 343 + kw * 49 + kd * 7;
        _Float16 v0 = (j0 < 7) ? (_Float16)wb[j0] : (_Float16)0.f;
        _Float16 v1 = (j1 < 7) ? (_Float16)wb[j1] : (_Float16)0.f;
        outv = pack2(v0, v1);
    }
    ((u32*)A2)[i] = outv;
}

// ---------------- conv1: 32x32x16 MFMA, windowed LDS, 4 waves ----------------
// block=(b,OH,OWp): M=30=(dw2,dh3,oc5), N=288=(u2,od12,ot12) -> 9 nt,
// K = 9 se x 28 k2(2 taps x kt8). slab row stride 52 (write-perfect, 13*tid mod 8 uniform).
// Wave balance: waves own tiles {w, w+4}; tile 8 ROTATES by k2 ((k2&3)==wave) ->
// every wave does 2.25 MFMA + 3.25 reads per k2 (no 50% wave0 straggler).
// Tile-8 acc is a 4-way partial; summed in a one-time LDS epilogue.
// A via persistent bank-padded LDS gather table (see pack_A1p):
//   lane addr = AOFF + kh*1164 + 4oc - 164dw + (164we + 20kd)   [we,kd compile-time per (k2,g)]
//   invalid kh/kw -> zero slot at kh=7 (+164 bias). junk lanes (col>=30): clamp+offset.
#define C1_SLAB 9360
#define C1_AOFF 9360
#define C1_LDS  (9360 + 9728)                    // 76.35 KB
__global__ __launch_bounds__(256, 2) void conv1_mfma(
    const float* __restrict__ x, const _Float16* __restrict__ A1,
    const float* __restrict__ b1, _Float16* __restrict__ h1)
{
    __shared__ u32 lds[C1_LDS];
    int tid = threadIdx.x;
    int lane = tid & 63;
    int wave = tid >> 6;
    int col = lane & 31;
    int g = lane >> 5;

    int bid = (int)blockIdx.x;                   // 1536 = 8*192
    int lbid = (bid & 7) * 192 + (bid >> 3);     // XCD chunk swizzle
    int OWp = lbid % 3;
    int OH = (lbid / 3) & 3;
    int b = lbid / 12;

    int qn[3], u_[2], od_[2], ot_[2];
    #pragma unroll
    for (int s = 0; s < 2; ++s) {
        int nt = wave + 4 * s;
        int n = nt * 32 + col;
        int u = n / 144, r2 = n % 144;
        int od = r2 / 12, ot = r2 % 12;
        u_[s] = u; od_[s] = od; ot_[s] = ot;
        qn[s] = (u * 36 + od) * 52 + ot * 4;
    }
    {   // tile 8 (all waves): n = 256+col -> u=1, r2=112+col
        int r2 = 112 + col;
        int od = r2 / 12, ot = r2 % 12;
        qn[2] = (36 + od) * 52 + ot * 4;
    }

    f32x16 acc0, acc1, acc2;
    #pragma unroll
    for (int q = 0; q < 16; ++q) { acc0[q] = 0.f; acc1[q] = 0.f; acc2[q] = 0.f; }

    const float* xbase = x + (size_t)b * 104976;
    int w10 = tid / 18, id18 = tid % 18;
    int iw = 4 * OWp + w10;
    bool stager = (tid < 180);

    // lane A-gather constants (bank-perfect layout)
    int mc = (col < 30) ? col : 29;
    int am_dw = mc / 15, am_dh = (mc % 15) / 5, am_oc = mc % 5;
    int jadd = 4 * (col - mc);                   // 0; 4/8 for col 30/31
    int vlane = 4 * am_oc - 164 * am_dw + jadd;
    int zbase = C1_AOFF + 8312 + vlane;          // zero slot (kh=7 +164 bias)
    bool eLo = (am_dw == 1);                     // we==0 edge (k2<=2)
    bool e3  = (am_dw == 1) && (g == 0);         // k2==3, tap0 we==0
    bool e24 = (am_dw == 0) && (g == 1);         // k2==24, tap1 we==7
    bool eHi = (am_dw == 0);                     // we==7 edge (k2>=25)

    float2 xr[9];
    {   // prologue: A' table into LDS; preload x(se=0)
        const uint4* asrc = (const uint4*)A1;
        uint4* adst = (uint4*)(lds + C1_AOFF);
        #pragma unroll
        for (int i = 0; i < 10; ++i) {
            int q = tid + 256 * i;
            if (q < 2432) adst[q] = asrc[q];
        }
        if (stager) {
            const float2* src = (const float2*)(xbase + (3 * OH) * 5832 + iw * 324 + id18 * 18);
            #pragma unroll
            for (int q = 0; q < 9; ++q) xr[q] = src[q];
        }
    }

    for (int se = 0; se < 9; ++se) {
        int kh = se - am_dh;
        int vbase = (kh >= 0 && kh < 7) ? (C1_AOFF + kh * 1164 + vlane) : zbase;

        __syncthreads();                         // prior compute done (covers prologue at se=0)
        if (stager) {
            _Float16 h[19];
            #pragma unroll
            for (int q = 0; q < 9; ++q) { h[2*q] = (_Float16)xr[q].x; h[2*q+1] = (_Float16)xr[q].y; }
            h[18] = (_Float16)0.f;
            u32 e[9], o[9];
            #pragma unroll
            for (int q = 0; q < 9; ++q) e[q] = pack2(h[2*q], h[2*q+1]);
            #pragma unroll
            for (int q = 0; q < 9; ++q) o[q] = pack2(h[2*q+1], (q < 8) ? h[2*q+2] : h[18]);
            int base = tid * 52;
            #pragma unroll
            for (int ot = 0; ot < 12; ++ot) {
                uint4 w;
                if ((ot & 1) == 0) { const int q = ot >> 1;   w = (uint4){e[q], e[q+1], e[q+2], e[q+3]}; }
                else               { const int q = (ot-1)>>1; w = (uint4){o[q], o[q+1], o[q+2], o[q+3]}; }
                *(uint4*)(&lds[base + ot * 4]) = w;
            }
        }
        __syncthreads();

        if (se < 8 && stager) {                  // prefetch next stage into regs
            const float2* src = (const float2*)(xbase + (3 * OH + se + 1) * 5832 + iw * 324 + id18 * 18);
            #pragma unroll
            for (int q = 0; q < 9; ++q) xr[q] = src[q];
        }

        #pragma unroll
        for (int k2 = 0; k2 < 28; ++k2) {
            const int t0 = 2 * k2, t1 = 2 * k2 + 1;
            const int c0 = ((t0 / 7) * 18 + (t0 % 7)) * 52;
            const int c1 = ((t1 / 7) * 18 + (t1 % 7)) * 52;
            const int ca0 = 164 * (t0 / 7) + 20 * (t0 % 7);
            const int ca1 = 164 * (t1 / 7) + 20 * (t1 % 7);
            int qoff = g ? c1 : c0;
            int ca   = g ? ca1 : ca0;
            int abase;
            if (k2 <= 2)       abase = eLo ? zbase : vbase;
            else if (k2 == 3)  abase = e3  ? zbase : vbase;
            else if (k2 == 24) abase = e24 ? zbase : vbase;
            else if (k2 >= 25) abase = eHi ? zbase : vbase;
            else               abase = vbase;
            f16x8 af = *(const f16x8*)(lds + abase + ca);
            f16x8 bf0 = *(const f16x8*)(lds + qn[0] + qoff);
            f16x8 bf1 = *(const f16x8*)(lds + qn[1] + qoff);
            acc0 = __builtin_amdgcn_mfma_f32_32x32x16_f16(af, bf0, acc0, 0, 0, 0);
            acc1 = __builtin_amdgcn_mfma_f32_32x32x16_f16(af, bf1, acc1, 0, 0, 0);
            if ((k2 & 3) == wave) {              // rotating tile-8 owner (wave-uniform)
                f16x8 bf2 = *(const f16x8*)(lds + qn[2] + qoff);
                acc2 = __builtin_amdgcn_mfma_f32_32x32x16_f16(af, bf2, acc2, 0, 0, 0);
            }
        }
    }

    // store tiles 0..7: C row = (r&3)+8*(r>>2)+4*g -> m = dw*15+dh*5+oc
    #pragma unroll
    for (int s = 0; s < 2; ++s) {
        f32x16 a = (s == 0) ? acc0 : acc1;
        int ow_b = 4 * OWp + 2 * u_[s];
        #pragma unroll
        for (int r = 0; r < 16; ++r) {
            const int m0 = (r & 3) + 8 * (r >> 2);
            const int m1 = m0 + 4;
            const int dw0 = m0 / 15, dh0 = (m0 % 15) / 5, oc0 = m0 % 5;
            const int dw1 = m1 / 15, dh1 = (m1 % 15) / 5, oc1 = m1 % 5;
            if (m1 >= 30 && g) continue;
            int dw = g ? dw1 : dw0;
            int dh = g ? dh1 : dh0;
            int oc = g ? oc1 : oc0;
            float bv = g ? b1[oc1] : b1[oc0];
            float v = fmaxf(a[r] + bv, 0.f);
            h1[(size_t)b * 103680 + oc * 20736 + (3 * OH + dh) * 1728
               + (ow_b + dw) * 144 + od_[s] * 12 + ot_[s]] = (_Float16)v;
        }
    }

    // epilogue: tile 8 = sum of 4 per-wave partials via LDS (slab area, compute done)
    __syncthreads();
    {
        float* fl = (float*)lds;
        #pragma unroll
        for (int r = 0; r < 16; ++r)
            fl[wave * 1024 + r * 64 + lane] = acc2[r];
    }
    __syncthreads();
    {
        const float* fl = (const float*)lds;
        int r2 = 112 + col;                      // tile 8: u=1
        int od = r2 / 12, ot = r2 % 12;
        int ow_b = 4 * OWp + 2;
        #pragma unroll
        for (int q = 0; q < 4; ++q) {
            int r = wave * 4 + q;                // this wave reduces rows r
            int m = (r & 3) + 8 * (r >> 2) + 4 * g;
            if (m >= 30) continue;
            float s = fl[r * 64 + lane] + fl[1024 + r * 64 + lane]
                    + fl[2048 + r * 64 + lane] + fl[3072 + r * 64 + lane];
            int dw = m / 15, dh = (m % 15) / 5, oc = m % 5;
            float v = fmaxf(s + b1[oc], 0.f);
            h1[(size_t)b * 103680 + oc * 20736 + (3 * OH + dh) * 1728
               + (ow_b + dw) * 144 + od * 12 + ot] = (_Float16)v;
        }
    }
}

// ---------------- conv2: 32x32x16 MFMA, gather-A table, ci-split ----------------
// block=(b,OH2,ci): M=30=(dh3,oc10), N=216 -> 7 nt, K = 9 she x 25 k2.
// A via persistent bank-padded gather table (per ci, see pack_A2p):
//   lane addr = AOFF + kh*1976 + 4oc + (280kw + 40kd)  [kw,kd compile-time per (k2,g)]
//   invalid kh or tap49 -> zero slot (kh=7 row). No per-she A restaging.
#define C2_SLAB 4032
#define C2_AOFF 4032
#define C2_LDS  (4032 + 15808)                   // 77.5 KB -> 2 blocks/CU
__global__ __launch_bounds__(256, 2) void conv2_mfma(
    const _Float16* __restrict__ h1, const _Float16* __restrict__ A2,
    _Float16* __restrict__ part)
{
    __shared__ u32 lds[C2_LDS];
    int tid = threadIdx.x;
    int lane = tid & 63;
    int wave = tid >> 6;
    int col = lane & 31;
    int g = lane >> 5;

    int bid = (int)blockIdx.x;                   // 1280 = 8*160
    int lbid = (bid & 7) * 160 + (bid >> 3);
    int ci = lbid % 5;
    int OH2 = (lbid / 5) & 1;
    int b = lbid / 10;

    int qn[2], n_[2];
    #pragma unroll
    for (int s = 0; s < 2; ++s) {
        int nt = wave + 4 * s;
        int n = nt * 32 + col;                   // nt<=6 -> n<224
        n_[s] = n;
        int nc = (n < 216) ? n : 215;
        int ow = nc / 36, rem = nc % 36;
        int od = rem / 6, ot = rem % 6;
        qn[s] = (ow * 12 + od) * 28 + ot * 4;
    }

    f32x16 acc0, acc1;
    #pragma unroll
    for (int q = 0; q < 16; ++q) { acc0[q] = 0.f; acc1[q] = 0.f; }

    const _Float16* hbase = h1 + (size_t)b * 103680 + ci * 20736;
    int iw = tid / 12, id12 = tid % 12;
    bool stager = (tid < 144);

    // lane A-gather constants
    int mc = (col < 30) ? col : 29;
    int am_dh = mc / 10, am_oc = mc % 10;
    int jadd = 4 * (col - mc);                   // 0; 4/8 for col 30/31
    int vlane = 4 * am_oc + jadd;
    int zb = C2_AOFF + 13832 + vlane;            // kh=7 zero row

    uint2 xr[3];
    {   // prologue: table into LDS (3952 uint4); preload h1(she=0)
        const uint4* asrc = (const uint4*)A2 + (size_t)ci * 3952;
        uint4* adst = (uint4*)(lds + C2_AOFF);
        #pragma unroll
        for (int i = 0; i < 16; ++i) {
            int q = tid + 256 * i;
            if (q < 3952) adst[q] = asrc[q];
        }
        if (stager) {
            const uint2* src = (const uint2*)(hbase + (3 * OH2) * 1728 + iw * 144 + id12 * 12);
            #pragma unroll
            for (int q = 0; q < 3; ++q) xr[q] = src[q];
        }
    }

    for (int she = 0; she < 9; ++she) {
        int kh = she - am_dh;
        int vb = (kh >= 0 && kh < 7) ? (C2_AOFF + kh * 1976 + vlane) : zb;

        __syncthreads();                         // prior compute done (covers prologue at she=0)
        if (stager) {
            _Float16 h[14];
            *(uint2*)&h[0] = xr[0]; *(uint2*)&h[4] = xr[1]; *(uint2*)&h[8] = xr[2];
            h[12] = (_Float16)0.f;
            u32 e[6], o[6];
            #pragma unroll
            for (int q = 0; q < 6; ++q) e[q] = pack2(h[2*q], h[2*q+1]);
            #pragma unroll
            for (int q = 0; q < 6; ++q) o[q] = pack2(h[2*q+1], (q < 5) ? h[2*q+2] : h[12]);
            int base = tid * 28;
            #pragma unroll
            for (int ot = 0; ot < 6; ++ot) {
                uint4 w;
                if ((ot & 1) == 0) { const int q = ot >> 1;   w = (uint4){e[q], e[q+1], e[q+2], e[q+3]}; }
                else               { const int q = (ot-1)>>1; w = (uint4){o[q], o[q+1], o[q+2], o[q+3]}; }
                *(uint4*)(&lds[base + ot * 4]) = w;
            }
        }
        __syncthreads();

        if (she < 8 && stager) {                 // prefetch next stage into regs
            const uint2* src = (const uint2*)(hbase + (3 * OH2 + she + 1) * 1728 + iw * 144 + id12 * 12);
            #pragma unroll
            for (int q = 0; q < 3; ++q) xr[q] = src[q];
        }

        #pragma unroll
        for (int k2 = 0; k2 < 25; ++k2) {
            const int t0 = 2 * k2, t1 = 2 * k2 + 1;
            const int c0 = ((t0 / 7) * 12 + (t0 % 7)) * 28;
            const int c1 = (t1 < 49) ? ((t1 / 7) * 12 + (t1 % 7)) * 28 : 0;
            const int a0 = 280 * (t0 / 7) + 40 * (t0 % 7);
            const int a1 = (t1 < 49) ? (280 * (t1 / 7) + 40 * (t1 % 7)) : 0;
            int qoff = g ? c1 : c0;
            int ca   = g ? a1 : a0;
            int ab = (k2 == 24 && g) ? zb : vb;  // tap 49 invalid
            f16x8 af = *(const f16x8*)(lds + ab + ca);
            f16x8 bf0 = *(const f16x8*)(lds + qn[0] + qoff);
            acc0 = __builtin_amdgcn_mfma_f32_32x32x16_f16(af, bf0, acc0, 0, 0, 0);
            if (wave < 3) {
                f16x8 bf1 = *(const f16x8*)(lds + qn[1] + qoff);
                acc1 = __builtin_amdgcn_mfma_f32_32x32x16_f16(af, bf1, acc1, 0, 0, 0);
            }
        }
    }

    // store partials: part[ci][b*6+oh][oc][216]; m = dh*10+oc
    #pragma unroll
    for (int s = 0; s < 2; ++s) {
        if (s == 1 && wave >= 3) continue;
        if (n_[s] >= 216) continue;
        f32x16 a = (s == 0) ? acc0 : acc1;
        #pragma unroll
        for (int r = 0; r < 16; ++r) {
            const int m0 = (r & 3) + 8 * (r >> 2);
            const int m1 = m0 + 4;
            const int dh0 = m0 / 10, oc0 = m0 % 10;
            const int dh1 = m1 / 10, oc1 = m1 % 10;
            if (m1 >= 30 && g) continue;
            int dh = g ? dh1 : dh0;
            int oc = g ? oc1 : oc0;
            int oh = 3 * OH2 + dh;
            part[((size_t)(ci * 768 + b * 6 + oh) * 10 + oc) * 216 + n_[s]] = (_Float16)a[r];
        }
    }
}

// ---------------- fused: 5-ci reduce + bias + ReLU + linear + sigmoid ----------------
__global__ __launch_bounds__(256) void out_fused(
    const _Float16* __restrict__ part, const float* __restrict__ b2,
    const float* __restrict__ wl, const float* __restrict__ bl,
    float* __restrict__ out)
{
    int b = blockIdx.x;
    int tid = threadIdx.x;
    float s = 0.f;
    for (int i = tid; i < 12960; i += 256) {
        int oc = i / 1296;
        int rem = i % 1296;
        int oh = rem / 216;
        int n = rem % 216;
        float v = 0.f;
        #pragma unroll
        for (int ci = 0; ci < 5; ++ci)
            v += (float)part[((size_t)(ci * 768 + b * 6 + oh) * 10 + oc) * 216 + n];
        v = fmaxf(v + b2[oc], 0.f);
        s += v * wl[i];
    }
    #pragma unroll
    for (int off = 32; off > 0; off >>= 1)
        s += __shfl_down(s, off, 64);
    __shared__ float wsum[4];
    int wave = tid >> 6;
    if ((tid & 63) == 0) wsum[wave] = s;
    __syncthreads();
    if (tid == 0) {
        float tot = wsum[0] + wsum[1] + wsum[2] + wsum[3] + bl[0];
        out[b] = 1.f / (1.f + expf(-tot));
    }
}

extern "C" void kernel_launch(void* const* d_in, const int* in_sizes, int n_in,
                              void* d_out, int out_size, void* d_ws, size_t ws_size,
                              hipStream_t stream) {
    const float* x  = (const float*)d_in[0];
    const float* w1 = (const float*)d_in[1];
    const float* b1 = (const float*)d_in[2];
    const float* w2 = (const float*)d_in[3];
    const float* b2 = (const float*)d_in[4];
    const float* wl = (const float*)d_in[5];
    const float* bl = (const float*)d_in[6];
    float* out = (float*)d_out;

    _Float16* h1   = (_Float16*)d_ws;            // 13,271,040
    _Float16* A1   = h1 + 13271040;              //    129,024 (19,456 used)
    _Float16* A2   = A1 + 129024;                //    576,000 (158,080 used)
    _Float16* part = A2 + 576000;                //  8,294,400

    pack_A1p<<<38, 256, 0, stream>>>(w1, A1);
    pack_A2p<<<309, 256, 0, stream>>>(w2, A2);
    conv1_mfma<<<1536, 256, 0, stream>>>(x, A1, b1, h1);
    conv2_mfma<<<1280, 256, 0, stream>>>(h1, A2, part);
    out_fused<<<128, 256, 0, stream>>>(part, b2, wl, bl, out);
}